// Round 1
// baseline (459.397 us; speedup 1.0000x reference)
//
#include <hip/hip_runtime.h>
#include <hip/hip_cooperative_groups.h>

namespace cg = cooperative_groups;

#define NUMH 8
#define HD 256
#define HID 2048
#define LIDX 5
#define MAXS 8192
#define NB 256
#define NT 256

__device__ __forceinline__ float wsum(float v) {
#pragma unroll
  for (int m = 32; m >= 1; m >>= 1) v += __shfl_xor(v, m, 64);
  return v;
}
__device__ __forceinline__ float wmax(float v) {
#pragma unroll
  for (int m = 32; m >= 1; m >>= 1) v = fmaxf(v, __shfl_xor(v, m, 64));
  return v;
}

// ws layout (floats): [0,2560) qkv vector; [2560,4608) attn accumulator;
// [4608,4616) softmax denominators (8 heads)
__global__ __launch_bounds__(NT) void attn_fused(
    const float* __restrict__ hidden, const float* __restrict__ cosb,
    const float* __restrict__ sinb, const int* __restrict__ idxp,
    const float* __restrict__ kcache, const float* __restrict__ vcache,
    const float* __restrict__ qkvw, const float* __restrict__ ow,
    const float* __restrict__ qnw, const float* __restrict__ knw,
    float* __restrict__ out, float* __restrict__ ws) {
  cg::grid_group grid = cg::this_grid();
  const int tid = threadIdx.x;
  const int lane = tid & 63;
  const int wave = tid >> 6;
  const int blk = blockIdx.x;
  const int gw = blk * 4 + wave;

  float* ws_qkv = ws;              // 2560 floats
  float* ws_acc = ws + 2560;       // 2048 floats
  float* ws_l   = ws + 2560 + 2048; // 8 floats

  __shared__ float qs[NUMH][HD];     // normalized+roped q, scaled
  __shared__ float ksh[HD];          // normalized+roped new k
  __shared__ float accsh[4][2048];   // per-wave attention partials (reused as x in phase 3)
  __shared__ float lsh[4][8];

  // zero global accumulators (done by block 0 before first grid sync)
  if (blk == 0) {
    for (int i = tid; i < 2056; i += NT) ws_acc[i] = 0.0f;
  }

  // ---------------- Phase 1: qkv = qkv_w @ hidden (2560 x 2048) ----------------
  float4 h4[8];
#pragma unroll
  for (int i = 0; i < 8; ++i) h4[i] = ((const float4*)hidden)[lane + 64 * i];
  for (int r = gw; r < 2560; r += NB * 4) {
    const float4* wr = (const float4*)(qkvw + (size_t)r * HID);
    float a = 0.f;
#pragma unroll
    for (int i = 0; i < 8; ++i) {
      float4 w4 = wr[lane + 64 * i];
      a += w4.x * h4[i].x + w4.y * h4[i].y + w4.z * h4[i].z + w4.w * h4[i].w;
    }
    a = wsum(a);
    if (lane == 0) ws_qkv[r] = a;
  }
  grid.sync();

  // ------------- Phase 2a: ane_rmsnorm + rope for q heads (0..7) and k (task 8) -------------
  const int idx = idxp[0];
  for (int task = wave; task < 9; task += 4) {
    const bool isk = (task == 8);
    const float* src = ws_qkv + task * HD;  // task 8 lands on k rows (8*256)
    const float* nw = isk ? knw : qnw;
    float4 x = ((const float4*)src)[lane];
    float m = fmaxf(fmaxf(fabsf(x.x), fabsf(x.y)), fmaxf(fabsf(x.z), fabsf(x.w)));
    m = wmax(m);
    m = fmaxf(m, 5.9604644775390625e-8f);  // 2^-24 clip
    float xs0 = x.x / m, xs1 = x.y / m, xs2 = x.z / m, xs3 = x.w / m;
    float ss = wsum(xs0 * xs0 + xs1 * xs1 + xs2 * xs2 + xs3 * xs3);
    float rs = rsqrtf(ss) * 16.0f;  // sqrt(256) folded in
    float4 nwv = ((const float4*)nw)[lane];
    float n0 = rs * xs0 * (1.f + nwv.x);
    float n1 = rs * xs1 * (1.f + nwv.y);
    float n2 = rs * xs2 * (1.f + nwv.z);
    float n3 = rs * xs3 * (1.f + nwv.w);
    // rotate_half: dim d pairs with d^128 -> lane^32, negate for d<128
    float p0 = __shfl_xor(n0, 32, 64);
    float p1 = __shfl_xor(n1, 32, 64);
    float p2 = __shfl_xor(n2, 32, 64);
    float p3 = __shfl_xor(n3, 32, 64);
    float sgn = (lane < 32) ? -1.f : 1.f;
    float4 c4 = ((const float4*)cosb)[lane];
    float4 s4 = ((const float4*)sinb)[lane];
    float scl = isk ? 1.0f : 0.0625f;  // q gets SCALING = 256^-0.5
    float4 o4;
    o4.x = (n0 * c4.x + sgn * p0 * s4.x) * scl;
    o4.y = (n1 * c4.y + sgn * p1 * s4.y) * scl;
    o4.z = (n2 * c4.z + sgn * p2 * s4.z) * scl;
    o4.w = (n3 * c4.w + sgn * p3 * s4.w) * scl;
    float* dst = isk ? ksh : qs[task];
    ((float4*)dst)[lane] = o4;
  }
  __syncthreads();

  // ------------- Phase 2b: attention over this block's position chunk -------------
  float4 qf[NUMH];
#pragma unroll
  for (int h = 0; h < NUMH; ++h) qf[h] = ((const float4*)qs[h])[lane];

  const int S = idx + 1;                 // valid positions 0..idx
  const int chunk = (S + NB - 1) / NB;
  const int s0 = blk * chunk;
  const int s1 = min(S, s0 + chunk);
  float4 av[NUMH];
  float lacc[NUMH];
#pragma unroll
  for (int h = 0; h < NUMH; ++h) {
    av[h] = make_float4(0.f, 0.f, 0.f, 0.f);
    lacc[h] = 0.f;
  }

  const float* kbase = kcache + (size_t)LIDX * MAXS * HD;
  const float* vbase = vcache + (size_t)LIDX * MAXS * HD;
  for (int s = s0 + wave; s < s1; s += 4) {
    float4 k4, v4;
    if (s == idx) {  // freshly-written position: use new k (roped) / raw v
      k4 = ((const float4*)ksh)[lane];
      v4 = ((const float4*)(ws_qkv + (NUMH + 1) * HD))[lane];
    } else {
      k4 = ((const float4*)(kbase + (size_t)s * HD))[lane];
      v4 = ((const float4*)(vbase + (size_t)s * HD))[lane];
    }
    float sc[NUMH];
#pragma unroll
    for (int h = 0; h < NUMH; ++h)
      sc[h] = qf[h].x * k4.x + qf[h].y * k4.y + qf[h].z * k4.z + qf[h].w * k4.w;
#pragma unroll
    for (int m = 32; m >= 1; m >>= 1) {
#pragma unroll
      for (int h = 0; h < NUMH; ++h) sc[h] += __shfl_xor(sc[h], m, 64);
    }
#pragma unroll
    for (int h = 0; h < NUMH; ++h) {
      float t = tanhf(sc[h] * 0.02f) * 50.0f;  // softcap; bounded by +/-50
      float p = __expf(t - 50.0f);             // static softmax max = 50
      lacc[h] += p;
      av[h].x += p * v4.x;
      av[h].y += p * v4.y;
      av[h].z += p * v4.z;
      av[h].w += p * v4.w;
    }
  }
  // combine the 4 waves in LDS, then one global atomic per element
#pragma unroll
  for (int h = 0; h < NUMH; ++h) ((float4*)&accsh[wave][h * HD])[lane] = av[h];
  if (lane == 0) {
#pragma unroll
    for (int h = 0; h < NUMH; ++h) lsh[wave][h] = lacc[h];
  }
  __syncthreads();
  for (int i = tid; i < 2048; i += NT) {
    float v = accsh[0][i] + accsh[1][i] + accsh[2][i] + accsh[3][i];
    atomicAdd(&ws_acc[i], v);
  }
  if (tid < 8) {
    float v = lsh[0][tid] + lsh[1][tid] + lsh[2][tid] + lsh[3][tid];
    atomicAdd(&ws_l[tid], v);
  }
  grid.sync();

  // ---------------- Phase 3: out = o_w @ (acc / l) (2048 x 2048) ----------------
  float* xsh = accsh[0];  // reuse LDS
  for (int i = tid; i < 2048; i += NT) xsh[i] = ws_acc[i] / ws_l[i >> 8];
  __syncthreads();
  for (int r = gw; r < 2048; r += NB * 4) {
    const float4* wr = (const float4*)(ow + (size_t)r * HID);
    float a = 0.f;
#pragma unroll
    for (int i = 0; i < 8; ++i) {
      float4 w4 = wr[lane + 64 * i];
      float4 x4 = ((const float4*)xsh)[lane + 64 * i];
      a += w4.x * x4.x + w4.y * x4.y + w4.z * x4.z + w4.w * x4.w;
    }
    a = wsum(a);
    if (lane == 0) out[r] = a;
  }
}

extern "C" void kernel_launch(void* const* d_in, const int* in_sizes, int n_in,
                              void* d_out, int out_size, void* d_ws, size_t ws_size,
                              hipStream_t stream) {
  const float* hidden = (const float*)d_in[0];
  const float* cosb   = (const float*)d_in[1];
  const float* sinb   = (const float*)d_in[2];
  const int*   idxp   = (const int*)d_in[3];
  const float* kcache = (const float*)d_in[4];
  const float* vcache = (const float*)d_in[5];
  // d_in[6] = mask: fully determined by idx (0 for s<=idx else -1e9); not needed
  const float* qkvw   = (const float*)d_in[7];
  const float* ow     = (const float*)d_in[8];
  const float* qnw    = (const float*)d_in[9];
  const float* knw    = (const float*)d_in[10];
  float* out = (float*)d_out;
  float* ws  = (float*)d_ws;

  void* args[] = {&hidden, &cosb, &sinb, &idxp, &kcache, &vcache,
                  &qkvw, &ow, &qnw, &knw, &out, &ws};
  hipLaunchCooperativeKernel(attn_fused, dim3(NB), dim3(NT), args, 0, stream);
}

// Round 2
// 379.534 us; speedup vs baseline: 1.2104x; 1.2104x over previous
//
#include <hip/hip_runtime.h>

#define NUMH 8
#define HD 256
#define HID 2048
#define LIDX 5
#define MAXS 8192

__device__ __forceinline__ float wsum(float v) {
#pragma unroll
  for (int m = 32; m >= 1; m >>= 1) v += __shfl_xor(v, m, 64);
  return v;
}
__device__ __forceinline__ float wmax(float v) {
#pragma unroll
  for (int m = 32; m >= 1; m >>= 1) v = fmaxf(v, __shfl_xor(v, m, 64));
  return v;
}

// ws layout (floats): [0,2560) qkv vector; [2560,4608) attn accumulator;
// [4608,4616) softmax denominators (8 heads)

// ---------------- K1: qkv = qkv_w @ hidden (2560 x 2048), wave per row ----------------
__global__ __launch_bounds__(256) void k_qkv(const float* __restrict__ qkvw,
                                             const float* __restrict__ hidden,
                                             float* __restrict__ ws) {
  const int lane = threadIdx.x & 63;
  const int wave = threadIdx.x >> 6;
  // block 0 zeros the attention accumulators for K2
  if (blockIdx.x == 0) {
    for (int i = threadIdx.x; i < 2056; i += 256) ws[2560 + i] = 0.0f;
  }
  const int r = blockIdx.x * 4 + wave;  // 640 blocks * 4 = 2560 rows
  const float4* wr = (const float4*)(qkvw + (size_t)r * HID);
  const float4* h = (const float4*)hidden;
  float a = 0.f;
#pragma unroll
  for (int i = 0; i < 8; ++i) {
    float4 w4 = wr[lane + 64 * i];
    float4 h4 = h[lane + 64 * i];
    a += w4.x * h4.x + w4.y * h4.y + w4.z * h4.z + w4.w * h4.w;
  }
  a = wsum(a);
  if (lane == 0) ws[r] = a;
}

// ---------------- K2: norm+rope (in-block) + attention over position chunk ----------------
__global__ __launch_bounds__(256) void k_attn(const float* __restrict__ cosb,
                                              const float* __restrict__ sinb,
                                              const int* __restrict__ idxp,
                                              const float* __restrict__ kcache,
                                              const float* __restrict__ vcache,
                                              const float* __restrict__ qnw,
                                              const float* __restrict__ knw,
                                              float* __restrict__ ws) {
  const int tid = threadIdx.x;
  const int lane = tid & 63;
  const int wave = tid >> 6;
  const int blk = blockIdx.x;
  const int NB = gridDim.x;

  float* ws_qkv = ws;
  float* ws_acc = ws + 2560;
  float* ws_l = ws + 2560 + 2048;

  __shared__ float qs[NUMH][HD];
  __shared__ float ksh[HD];
  __shared__ float accsh[4][2048];
  __shared__ float lsh[4][8];

  const int idx = idxp[0];
  // norm + rope: tasks 0..7 = q heads, task 8 = k
  for (int task = wave; task < 9; task += 4) {
    const bool isk = (task == 8);
    const float* src = ws_qkv + task * HD;
    const float* nw = isk ? knw : qnw;
    float4 x = ((const float4*)src)[lane];
    float m = fmaxf(fmaxf(fabsf(x.x), fabsf(x.y)), fmaxf(fabsf(x.z), fabsf(x.w)));
    m = wmax(m);
    m = fmaxf(m, 5.9604644775390625e-8f);
    float xs0 = x.x / m, xs1 = x.y / m, xs2 = x.z / m, xs3 = x.w / m;
    float ss = wsum(xs0 * xs0 + xs1 * xs1 + xs2 * xs2 + xs3 * xs3);
    float rs = rsqrtf(ss) * 16.0f;
    float4 nwv = ((const float4*)nw)[lane];
    float n0 = rs * xs0 * (1.f + nwv.x);
    float n1 = rs * xs1 * (1.f + nwv.y);
    float n2 = rs * xs2 * (1.f + nwv.z);
    float n3 = rs * xs3 * (1.f + nwv.w);
    float p0 = __shfl_xor(n0, 32, 64);
    float p1 = __shfl_xor(n1, 32, 64);
    float p2 = __shfl_xor(n2, 32, 64);
    float p3 = __shfl_xor(n3, 32, 64);
    float sgn = (lane < 32) ? -1.f : 1.f;
    float4 c4 = ((const float4*)cosb)[lane];
    float4 s4 = ((const float4*)sinb)[lane];
    float scl = isk ? 1.0f : 0.0625f;
    float4 o4;
    o4.x = (n0 * c4.x + sgn * p0 * s4.x) * scl;
    o4.y = (n1 * c4.y + sgn * p1 * s4.y) * scl;
    o4.z = (n2 * c4.z + sgn * p2 * s4.z) * scl;
    o4.w = (n3 * c4.w + sgn * p3 * s4.w) * scl;
    float* dst = isk ? ksh : qs[task];
    ((float4*)dst)[lane] = o4;
  }
  __syncthreads();

  float4 qf[NUMH];
#pragma unroll
  for (int h = 0; h < NUMH; ++h) qf[h] = ((const float4*)qs[h])[lane];

  const int S = idx + 1;
  const int chunk = (S + NB - 1) / NB;
  const int s0 = blk * chunk;
  const int s1 = min(S, s0 + chunk);
  float4 av[NUMH];
  float lacc[NUMH];
#pragma unroll
  for (int h = 0; h < NUMH; ++h) {
    av[h] = make_float4(0.f, 0.f, 0.f, 0.f);
    lacc[h] = 0.f;
  }

  const float* kbase = kcache + (size_t)LIDX * MAXS * HD;
  const float* vbase = vcache + (size_t)LIDX * MAXS * HD;
  for (int s = s0 + wave; s < s1; s += 4) {
    float4 k4, v4;
    if (s == idx) {
      k4 = ((const float4*)ksh)[lane];
      v4 = ((const float4*)(ws_qkv + (NUMH + 1) * HD))[lane];
    } else {
      k4 = ((const float4*)(kbase + (size_t)s * HD))[lane];
      v4 = ((const float4*)(vbase + (size_t)s * HD))[lane];
    }
    float sc[NUMH];
#pragma unroll
    for (int h = 0; h < NUMH; ++h)
      sc[h] = qf[h].x * k4.x + qf[h].y * k4.y + qf[h].z * k4.z + qf[h].w * k4.w;
#pragma unroll
    for (int m = 32; m >= 1; m >>= 1) {
#pragma unroll
      for (int h = 0; h < NUMH; ++h) sc[h] += __shfl_xor(sc[h], m, 64);
    }
#pragma unroll
    for (int h = 0; h < NUMH; ++h) {
      float t = tanhf(sc[h] * 0.02f) * 50.0f;
      float p = __expf(t - 50.0f);
      lacc[h] += p;
      av[h].x += p * v4.x;
      av[h].y += p * v4.y;
      av[h].z += p * v4.z;
      av[h].w += p * v4.w;
    }
  }
#pragma unroll
  for (int h = 0; h < NUMH; ++h) ((float4*)&accsh[wave][h * HD])[lane] = av[h];
  if (lane == 0) {
#pragma unroll
    for (int h = 0; h < NUMH; ++h) lsh[wave][h] = lacc[h];
  }
  __syncthreads();
  for (int i = tid; i < 2048; i += 256) {
    float v = accsh[0][i] + accsh[1][i] + accsh[2][i] + accsh[3][i];
    atomicAdd(&ws_acc[i], v);
  }
  if (tid < 8) {
    float v = lsh[0][tid] + lsh[1][tid] + lsh[2][tid] + lsh[3][tid];
    atomicAdd(&ws_l[tid], v);
  }
}

// ---------------- K3: out = o_w @ (acc / l) (2048 x 2048), wave per row ----------------
__global__ __launch_bounds__(256) void k_oproj(const float* __restrict__ ow,
                                               float* __restrict__ ws,
                                               float* __restrict__ out) {
  const int lane = threadIdx.x & 63;
  const int wave = threadIdx.x >> 6;
  const int r = blockIdx.x * 4 + wave;  // 512 blocks * 4 = 2048 rows
  const float* ws_acc = ws + 2560;
  const float* ws_l = ws + 2560 + 2048;
  const float4* wr = (const float4*)(ow + (size_t)r * HID);
  const float4* x = (const float4*)ws_acc;
  float a = 0.f;
#pragma unroll
  for (int i = 0; i < 8; ++i) {
    // float4 index lane+64*i covers elems 4*(lane+64i)..+3 -> head == i (uniform)
    float rl = 1.0f / ws_l[i];
    float4 w4 = wr[lane + 64 * i];
    float4 x4 = x[lane + 64 * i];
    a += w4.x * (x4.x * rl) + w4.y * (x4.y * rl) + w4.z * (x4.z * rl) +
         w4.w * (x4.w * rl);
  }
  a = wsum(a);
  if (lane == 0) out[r] = a;
}

extern "C" void kernel_launch(void* const* d_in, const int* in_sizes, int n_in,
                              void* d_out, int out_size, void* d_ws, size_t ws_size,
                              hipStream_t stream) {
  const float* hidden = (const float*)d_in[0];
  const float* cosb   = (const float*)d_in[1];
  const float* sinb   = (const float*)d_in[2];
  const int*   idxp   = (const int*)d_in[3];
  const float* kcache = (const float*)d_in[4];
  const float* vcache = (const float*)d_in[5];
  const float* qkvw   = (const float*)d_in[7];
  const float* ow     = (const float*)d_in[8];
  const float* qnw    = (const float*)d_in[9];
  const float* knw    = (const float*)d_in[10];
  float* out = (float*)d_out;
  float* ws  = (float*)d_ws;

  k_qkv<<<640, 256, 0, stream>>>(qkvw, hidden, ws);
  k_attn<<<256, 256, 0, stream>>>(cosb, sinb, idxp, kcache, vcache, qnw, knw, ws);
  k_oproj<<<512, 256, 0, stream>>>(ow, ws, out);
}